// Round 10
// baseline (152.551 us; speedup 1.0000x reference)
//
#include <hip/hip_runtime.h>

// rGIN fused: out = h + segment_sum(h[src], dst), h = [nodes | random_values]
// Round-10: counting-sort CSR build (round-8/9, proven) + NFB=2 feature-split
// aggregate: bt stored as 2 slabs [fb][N][64] bf16 (row-half = one aligned
// 128B line); aggregate blocks bind fb=blockIdx&1 so each XCD's L2 only
// streams a 12.8MB slab (halves the L2-fill traffic vs one 25.6MB table).

#define N_NODES 100000
#define NF      128
#define FP1     129
#define M_EDGES 1600000
#define SLOTS   32                     // bucket = 32*4B = one 128B line
#define SPILL_CAP 4096

#define BINSHIFT 8
#define BINNODES 256
#define NBINS    391                   // ceil(100000/256)
#define HIST_BLOCKS 256
#define CHUNK (M_EDGES / HIST_BLOCKS)  // 6250
#define CONV_BLOCKS 6250               // N*16 threads / 256

// round-5 fallback params
#define NSLICES 8
#define SLICE_NODES (N_NODES / NSLICES)
#define FILL_BLOCKS 1024
#define CONVB_BLOCKS 12500

__device__ inline unsigned short f2bf(float f) {
    unsigned int u = __float_as_uint(f);
    u += 0x7FFFu + ((u >> 16) & 1u);   // RNE
    return (unsigned short)(u >> 16);
}
__device__ inline unsigned int pack2(float a, float b) {
    return (unsigned int)f2bf(a) | ((unsigned int)f2bf(b) << 16);
}

// ---------------------------------------------------------------------------
// A: histogram blocks (LDS 391-bin hist of own chunk) + split-slab convert.
// Convert: thread u -> node n=u>>4, k=u&15; features k*8..k*8+7 go to slab
// fb=k>>3 at [n][ (k&7)*8 ], a 16B aligned uint4 store.
// ---------------------------------------------------------------------------
__global__ __launch_bounds__(256) void k_hist_convert(
    const float* __restrict__ nodes,
    unsigned short* __restrict__ bt,      // [2][N][64] bf16
    const int* __restrict__ ei,
    int* __restrict__ countsT)            // [NBINS][HIST_BLOCKS]
{
    int bid = blockIdx.x;
    if (bid >= HIST_BLOCKS) {
        int u = (bid - HIST_BLOCKS) * 256 + threadIdx.x;   // < 1,600,000 exactly
        int n = u >> 4, k = u & 15;
        const float4* s4 = reinterpret_cast<const float4*>(nodes + (size_t)n * NF + k * 8);
        float4 a = s4[0], b = s4[1];
        uint4 o;
        o.x = pack2(a.x, a.y); o.y = pack2(a.z, a.w);
        o.z = pack2(b.x, b.y); o.w = pack2(b.z, b.w);
        int fb = k >> 3, kk = k & 7;
        uint4* dp = reinterpret_cast<uint4*>(bt + (size_t)fb * N_NODES * 64
                                                + (size_t)n * 64 + kk * 8);
        *dp = o;
        return;
    }
    __shared__ int h[NBINS];
    for (int i = threadIdx.x; i < NBINS; i += 256) h[i] = 0;
    __syncthreads();
    int e0 = bid * CHUNK;
    for (int e = e0 + threadIdx.x; e < e0 + CHUNK; e += 256)
        atomicAdd(&h[ei[e] >> BINSHIFT], 1);
    __syncthreads();
    for (int i = threadIdx.x; i < NBINS; i += 256)
        countsT[i * HIST_BLOCKS + bid] = h[i];
}

// ---------------------------------------------------------------------------
// B1: per-bin exclusive scan of the 256 block-counts (in place) + bin total.
// ---------------------------------------------------------------------------
__global__ __launch_bounds__(256) void k_scan_bins(int* __restrict__ countsT,
                                                   int* __restrict__ binTotal)
{
    __shared__ int s[256];
    int bin = blockIdx.x;
    int v = countsT[bin * HIST_BLOCKS + threadIdx.x];
    s[threadIdx.x] = v;
    __syncthreads();
    for (int off = 1; off < 256; off <<= 1) {
        int t = (threadIdx.x >= off) ? s[threadIdx.x - off] : 0;
        __syncthreads();
        s[threadIdx.x] += t;
        __syncthreads();
    }
    countsT[bin * HIST_BLOCKS + threadIdx.x] = s[threadIdx.x] - v;  // exclusive
    if (threadIdx.x == 255) binTotal[bin] = s[255];
}

// ---------------------------------------------------------------------------
// B2: single-block exclusive scan of 391 bin totals; zeroes spillCount.
// ---------------------------------------------------------------------------
__global__ __launch_bounds__(512) void k_scan_base(const int* __restrict__ binTotal,
                                                   int* __restrict__ binBase,
                                                   int* __restrict__ spillCount)
{
    __shared__ int s[512];
    int v = (threadIdx.x < NBINS) ? binTotal[threadIdx.x] : 0;
    s[threadIdx.x] = v;
    __syncthreads();
    for (int off = 1; off < 512; off <<= 1) {
        int t = (threadIdx.x >= off) ? s[threadIdx.x - off] : 0;
        __syncthreads();
        s[threadIdx.x] += t;
        __syncthreads();
    }
    if (threadIdx.x < NBINS) binBase[threadIdx.x] = s[threadIdx.x] - v;
    if (threadIdx.x == 0) { binBase[NBINS] = M_EDGES; *spillCount = 0; }
}

// ---------------------------------------------------------------------------
// C: placement via LDS cursors (disjoint segments, no global atomics).
// ---------------------------------------------------------------------------
__global__ __launch_bounds__(256) void k_place(
    const int* __restrict__ ei,
    const int* __restrict__ countsT,
    const int* __restrict__ binBase,
    uint2* __restrict__ part)
{
    __shared__ int cur[NBINS];
    int bid = blockIdx.x;
    for (int i = threadIdx.x; i < NBINS; i += 256)
        cur[i] = binBase[i] + countsT[i * HIST_BLOCKS + bid];
    __syncthreads();
    int e0 = bid * CHUNK;
    for (int e = e0 + threadIdx.x; e < e0 + CHUNK; e += 256) {
        int dst = ei[e];
        int src = ei[M_EDGES + e];
        int pos = atomicAdd(&cur[dst >> BINSHIFT], 1);
        part[pos] = make_uint2((unsigned)dst, (unsigned)src);
    }
}

// ---------------------------------------------------------------------------
// D: per-bin bucket build in LDS -> dense writes.
// ---------------------------------------------------------------------------
__global__ __launch_bounds__(256) void k_bucket_build(
    const uint2* __restrict__ part,
    const int*   __restrict__ binBase,
    int* __restrict__ cursor,       // [N] clamped counts
    int* __restrict__ srclist,      // [N][SLOTS]
    int* __restrict__ spill,
    int* __restrict__ spillCount)
{
    __shared__ int s_cnt[BINNODES];
    __shared__ int s_bkt[BINNODES * SLOTS];   // 32 KB

    int bin = blockIdx.x;
    int nodeBase = bin << BINSHIFT;
    int nNodes = N_NODES - nodeBase;
    if (nNodes > BINNODES) nNodes = BINNODES;

    for (int i = threadIdx.x; i < BINNODES; i += 256) s_cnt[i] = 0;
    __syncthreads();

    int a = binBase[bin], b = binBase[bin + 1];
    for (int i = a + threadIdx.x; i < b; i += 256) {
        uint2 p = part[i];
        int local = (int)p.x - nodeBase;
        int pos = atomicAdd(&s_cnt[local], 1);
        if (pos < SLOTS) s_bkt[local * SLOTS + pos] = (int)p.y;
        else {
            int sp = atomicAdd(spillCount, 1);
            if (sp < SPILL_CAP) { spill[2 * sp] = (int)p.x; spill[2 * sp + 1] = (int)p.y; }
        }
    }
    __syncthreads();

    for (int i = threadIdx.x; i < nNodes; i += 256) {
        int c = s_cnt[i];
        cursor[nodeBase + i] = (c > SLOTS) ? SLOTS : c;
    }
    for (int i = threadIdx.x; i < nNodes * SLOTS; i += 256)
        srclist[(size_t)nodeBase * SLOTS + i] = s_bkt[i];
}

// ---------------------------------------------------------------------------
// E: NFB=2 feature-split aggregation. fb = blockIdx&1 (constant per block ->
// XCD-slab binding via mod-8 round-robin). Block = 4 waves = 4 nodes at this
// fb. Wave: two 32-lane halves, each processes one edge per gather: lane fl
// loads ushort2 (4B) at slab[s*64 + fl*2] -> 32 lanes = the full 128B aligned
// half-row in one line. Bucket register-resident; indices via __shfl.
// ---------------------------------------------------------------------------
__global__ __launch_bounds__(256) void k_aggregate_fb2(
    const unsigned short* __restrict__ bt,   // [2][N][64]
    const float* __restrict__ rv,
    const int*   __restrict__ cursor,
    const int*   __restrict__ srclist,
    float* __restrict__ out)
{
    int bid  = blockIdx.x;
    int fb   = bid & 1;
    int node = (bid >> 1) * 4 + (threadIdx.x >> 6);
    if (node >= N_NODES) return;
    int lane = threadIdx.x & 63;
    int sub  = lane >> 5;
    int fl   = lane & 31;

    int cnt = cursor[node];                    // clamped to SLOTS at build
    int b = srclist[(long long)node * SLOTS + fl];   // one 128B line per node

    const unsigned int* slab =
        reinterpret_cast<const unsigned int*>(bt + (size_t)fb * N_NODES * 64);

    float2 acc = make_float2(0.f, 0.f);

    #define EDGE2(uu) do {                                            \
        acc.x += __uint_as_float((uu) << 16);                          \
        acc.y += __uint_as_float((uu) & 0xFFFF0000u);                  \
    } while (0)

    int i = sub;
    for (; i + 6 < cnt; i += 8) {              // 4 edges per half per iter
        int s0 = __shfl(b, i,     32);
        int s1 = __shfl(b, i + 2, 32);
        int s2 = __shfl(b, i + 4, 32);
        int s3 = __shfl(b, i + 6, 32);
        unsigned int u0 = slab[s0 * 32 + fl];
        unsigned int u1 = slab[s1 * 32 + fl];
        unsigned int u2 = slab[s2 * 32 + fl];
        unsigned int u3 = slab[s3 * 32 + fl];
        EDGE2(u0); EDGE2(u1); EDGE2(u2); EDGE2(u3);
    }
    for (; i < cnt; i += 2) {
        int s0 = __shfl(b, i, 32);
        unsigned int u0 = slab[s0 * 32 + fl];
        EDGE2(u0);
    }

    acc.x += __shfl_xor(acc.x, 32);
    acc.y += __shfl_xor(acc.y, 32);

    if (sub == 0) {
        unsigned int su = slab[node * 32 + fl];          // self term
        acc.x += __uint_as_float(su << 16);
        acc.y += __uint_as_float(su & 0xFFFF0000u);
        float* o = out + (long long)node * FP1 + fb * 64 + fl * 2;
        o[0] = acc.x;
        o[1] = acc.y;
    }

    if (fb == 0 && sub == 0) {                 // rv column (one writer)
        float c = (fl < cnt) ? rv[b] : 0.f;
        c += __shfl_xor(c, 16, 32);
        c += __shfl_xor(c, 8, 32);
        c += __shfl_xor(c, 4, 32);
        c += __shfl_xor(c, 2, 32);
        c += __shfl_xor(c, 1, 32);
        if (fl == 0) out[(long long)node * FP1 + NF] = rv[node] + c;
    }
    #undef EDGE2
}

// ---------------------------------------------------------------------------
// Spill fixup: exact f32 atomic adds for bucket-overflow edges (~hundreds).
// ---------------------------------------------------------------------------
__global__ __launch_bounds__(256) void k_spill(
    const float* __restrict__ nodes, const float* __restrict__ rv,
    const int* __restrict__ spill, const int* __restrict__ spillCount,
    float* __restrict__ out)
{
    int n = *spillCount;
    if (n > SPILL_CAP) n = SPILL_CAP;
    int wave  = (int)((blockIdx.x * (long long)blockDim.x + threadIdx.x) >> 6);
    int nwave = (int)((gridDim.x * (long long)blockDim.x) >> 6);
    int lane  = threadIdx.x & 63;
    for (int e = wave; e < n; e += nwave) {
        int dst = spill[2 * e], src = spill[2 * e + 1];
        if (lane < 32) {
            float4 v = reinterpret_cast<const float4*>(nodes + (long long)src * NF)[lane];
            float* o = out + (long long)dst * FP1 + lane * 4;
            atomicAdd(o + 0, v.x); atomicAdd(o + 1, v.y);
            atomicAdd(o + 2, v.z); atomicAdd(o + 3, v.w);
        } else if (lane == 32) {
            atomicAdd(out + (long long)dst * FP1 + NF, rv[src]);
        }
    }
}

// ===========================================================================
// Fallback B: round-5 fused convert + sliced bucket fill + [N][128] aggregate.
// ===========================================================================
__global__ __launch_bounds__(256) void k_convert_fill(
    const float* __restrict__ nodes,
    unsigned short* __restrict__ bt,      // [N][128]
    const int* __restrict__ ei,
    int* __restrict__ cursor,
    int* __restrict__ srclist,
    int* __restrict__ spill,
    int* __restrict__ spillCount)
{
    int bid = blockIdx.x;
    if (bid < FILL_BLOCKS) {
        int slice = bid & (NSLICES - 1);
        int blk   = bid >> 3;
        const int nblk = FILL_BLOCKS >> 3;
        int lo = slice * SLICE_NODES, hi = lo + SLICE_NODES;
        for (int e = blk * 256 + threadIdx.x; e < M_EDGES; e += nblk * 256) {
            int dst = ei[e];
            int src = ei[M_EDGES + e];
            if (dst >= lo && dst < hi) {
                int pos = atomicAdd(&cursor[dst], 1);
                if (pos < SLOTS) srclist[dst * SLOTS + pos] = src;
                else {
                    int sp = atomicAdd(spillCount, 1);
                    if (sp < SPILL_CAP) { spill[2 * sp] = dst; spill[2 * sp + 1] = src; }
                }
            }
        }
    } else {
        int t = (bid - FILL_BLOCKS) * 256 + threadIdx.x;
        float4 v = reinterpret_cast<const float4*>(nodes)[t];
        ushort4 o;
        o.x = f2bf(v.x); o.y = f2bf(v.y); o.z = f2bf(v.z); o.w = f2bf(v.w);
        reinterpret_cast<ushort4*>(bt)[t] = o;
    }
}

__global__ __launch_bounds__(256) void k_aggregate_bucket(
    const unsigned short* __restrict__ bt,   // [N][128]
    const float* __restrict__ rv,
    const int*   __restrict__ cursor,
    const int*   __restrict__ srclist,
    float* __restrict__ out)
{
    int wave = (int)((blockIdx.x * (long long)blockDim.x + threadIdx.x) >> 6);
    if (wave >= N_NODES) return;
    const int node = wave;
    int lane = threadIdx.x & 63;
    int sub  = lane >> 5;
    int fl   = lane & 31;

    int cnt = cursor[node];
    int b = srclist[(long long)node * SLOTS + fl];

    float c = (fl < cnt) ? rv[b] : 0.f;
    c += __shfl_xor(c, 16, 32);
    c += __shfl_xor(c, 8, 32);
    c += __shfl_xor(c, 4, 32);
    c += __shfl_xor(c, 2, 32);
    c += __shfl_xor(c, 1, 32);

    float4 acc = make_float4(0.f, 0.f, 0.f, 0.f);
    #define BF4_TO_F4(d4, u4) do {                                   \
        d4.x = __uint_as_float((unsigned int)(u4).x << 16);           \
        d4.y = __uint_as_float((unsigned int)(u4).y << 16);           \
        d4.z = __uint_as_float((unsigned int)(u4).z << 16);           \
        d4.w = __uint_as_float((unsigned int)(u4).w << 16);           \
    } while (0)
    int i = sub;
    for (; i + 6 < cnt; i += 8) {
        int s0 = __shfl(b, i, 32), s1 = __shfl(b, i + 2, 32);
        int s2 = __shfl(b, i + 4, 32), s3 = __shfl(b, i + 6, 32);
        ushort4 u0 = reinterpret_cast<const ushort4*>(bt + (long long)s0 * NF)[fl];
        ushort4 u1 = reinterpret_cast<const ushort4*>(bt + (long long)s1 * NF)[fl];
        ushort4 u2 = reinterpret_cast<const ushort4*>(bt + (long long)s2 * NF)[fl];
        ushort4 u3 = reinterpret_cast<const ushort4*>(bt + (long long)s3 * NF)[fl];
        float4 v0, v1, v2, v3;
        BF4_TO_F4(v0, u0); BF4_TO_F4(v1, u1); BF4_TO_F4(v2, u2); BF4_TO_F4(v3, u3);
        acc.x += v0.x + v1.x; acc.y += v0.y + v1.y; acc.z += v0.z + v1.z; acc.w += v0.w + v1.w;
        acc.x += v2.x + v3.x; acc.y += v2.y + v3.y; acc.z += v2.z + v3.z; acc.w += v2.w + v3.w;
    }
    for (; i < cnt; i += 2) {
        int s0 = __shfl(b, i, 32);
        ushort4 u0 = reinterpret_cast<const ushort4*>(bt + (long long)s0 * NF)[fl];
        float4 v0; BF4_TO_F4(v0, u0);
        acc.x += v0.x; acc.y += v0.y; acc.z += v0.z; acc.w += v0.w;
    }
    acc.x += __shfl_xor(acc.x, 32); acc.y += __shfl_xor(acc.y, 32);
    acc.z += __shfl_xor(acc.z, 32); acc.w += __shfl_xor(acc.w, 32);
    if (sub == 0) {
        ushort4 su = reinterpret_cast<const ushort4*>(bt + (long long)node * NF)[fl];
        float4 self; BF4_TO_F4(self, su);
        acc.x += self.x; acc.y += self.y; acc.z += self.z; acc.w += self.w;
        float* o = out + (long long)node * FP1 + fl * 4;
        o[0] = acc.x; o[1] = acc.y; o[2] = acc.z; o[3] = acc.w;
        if (fl == 0) out[(long long)node * FP1 + NF] = rv[node] + c;
    }
    #undef BF4_TO_F4
}

// ===========================================================================
// Fallback D: atomic scatter.
// ===========================================================================
__global__ __launch_bounds__(256) void k_init_out(
    const float* __restrict__ nodes, const float* __restrict__ rv,
    float* __restrict__ out)
{
    long long idx = (long long)blockIdx.x * blockDim.x + threadIdx.x;
    const long long total = (long long)N_NODES * FP1;
    if (idx >= total) return;
    int node = (int)(idx / FP1);
    int f    = (int)(idx - (long long)node * FP1);
    out[idx] = (f < NF) ? nodes[(long long)node * NF + f] : rv[node];
}

__global__ __launch_bounds__(256) void k_scatter(
    const float* __restrict__ nodes, const float* __restrict__ rv,
    const int* __restrict__ ei, float* __restrict__ out)
{
    long long t = (long long)blockIdx.x * blockDim.x + threadIdx.x;
    int lane = (int)(t & 31);
    long long e = t >> 5;
    if (e >= M_EDGES) return;
    int dst = ei[e];
    int src = ei[M_EDGES + e];
    const float4* row = reinterpret_cast<const float4*>(nodes + (long long)src * NF);
    float4 v = row[lane];
    float* o = out + (long long)dst * FP1 + lane * 4;
    atomicAdd(o + 0, v.x); atomicAdd(o + 1, v.y);
    atomicAdd(o + 2, v.z); atomicAdd(o + 3, v.w);
    if (lane == 0) atomicAdd(out + (long long)dst * FP1 + NF, rv[src]);
}

extern "C" void kernel_launch(void* const* d_in, const int* in_sizes, int n_in,
                              void* d_out, int out_size, void* d_ws, size_t ws_size,
                              hipStream_t stream) {
    const float* nodes = (const float*)d_in[0];
    const int*   ei    = (const int*)d_in[1];
    const float* rv    = (const float*)d_in[2];
    float* out = (float*)d_out;

    const size_t bt_bytes     = (size_t)N_NODES * NF * 2;            // 25.6 MB
    const size_t part_bytes   = (size_t)M_EDGES * 8;                 // 12.8 MB
    const size_t srcl_bytes   = (size_t)N_NODES * SLOTS * 4;         // 12.8 MB
    const size_t cur_bytes    = (size_t)N_NODES * 4;                 // 0.4 MB
    const size_t countsT_b    = (size_t)NBINS * HIST_BLOCKS * 4;     // 0.4 MB
    const size_t binTotal_b   = (size_t)NBINS * 4;
    const size_t binBase_b    = (size_t)(NBINS + 1) * 4;
    const size_t spill_bytes  = (size_t)SPILL_CAP * 8;

    const size_t need_A = bt_bytes + part_bytes + srcl_bytes + cur_bytes
                        + countsT_b + binTotal_b + binBase_b + 4 + spill_bytes + 256;
    const size_t need_B = bt_bytes + cur_bytes + srcl_bytes + spill_bytes + 64;

    if (ws_size >= need_A) {
        // --- Path A: counting-sort CSR + NFB=2 slab aggregate ---
        char* w = (char*)d_ws;
        unsigned short* bt = (unsigned short*)w; w += bt_bytes;   // [2][N][64]
        uint2* part     = (uint2*)w; w += part_bytes;
        int* srclist    = (int*)w;   w += srcl_bytes;
        int* cursor     = (int*)w;   w += cur_bytes;
        int* countsT    = (int*)w;   w += countsT_b;
        int* binTotal   = (int*)w;   w += binTotal_b;
        int* binBase    = (int*)w;   w += binBase_b;
        int* spillCount = (int*)w;   w += 4;
        int* spill      = (int*)w;

        k_hist_convert<<<HIST_BLOCKS + CONV_BLOCKS, 256, 0, stream>>>(
            nodes, bt, ei, countsT);
        k_scan_bins<<<NBINS, 256, 0, stream>>>(countsT, binTotal);
        k_scan_base<<<1, 512, 0, stream>>>(binTotal, binBase, spillCount);
        k_place<<<HIST_BLOCKS, 256, 0, stream>>>(ei, countsT, binBase, part);
        k_bucket_build<<<NBINS, 256, 0, stream>>>(
            part, binBase, cursor, srclist, spill, spillCount);

        int aggBlocks = 2 * ((N_NODES + 3) / 4);            // 50000
        k_aggregate_fb2<<<aggBlocks, 256, 0, stream>>>(bt, rv, cursor, srclist, out);

        k_spill<<<16, 256, 0, stream>>>(nodes, rv, spill, spillCount, out);
    } else if (ws_size >= need_B) {
        // --- Path B: round-5 fused pipeline ([N][128] layout) ---
        char* w = (char*)d_ws;
        unsigned short* bt = (unsigned short*)w; w += bt_bytes;
        int* cursor     = (int*)w; w += cur_bytes;
        int* srclist    = (int*)w; w += srcl_bytes;
        int* spill      = (int*)w; w += spill_bytes;
        int* spillCount = (int*)w;

        hipMemsetAsync(cursor, 0, cur_bytes, stream);
        hipMemsetAsync(spillCount, 0, 4, stream);

        k_convert_fill<<<FILL_BLOCKS + CONVB_BLOCKS, 256, 0, stream>>>(
            nodes, bt, ei, cursor, srclist, spill, spillCount);

        long long threads = (long long)N_NODES * 64;
        int grid = (int)((threads + 255) / 256);
        k_aggregate_bucket<<<grid, 256, 0, stream>>>(bt, rv, cursor, srclist, out);

        k_spill<<<16, 256, 0, stream>>>(nodes, rv, spill, spillCount, out);
    } else {
        // --- Path D: atomic scatter ---
        long long total = (long long)N_NODES * FP1;
        k_init_out<<<(int)((total + 255) / 256), 256, 0, stream>>>(nodes, rv, out);
        long long threads = (long long)M_EDGES * 32;
        k_scatter<<<(int)((threads + 255) / 256), 256, 0, stream>>>(nodes, rv, ei, out);
    }
}

// Round 11
// 119.607 us; speedup vs baseline: 1.2754x; 1.2754x over previous
//
#include <hip/hip_runtime.h>

// rGIN fused: out = h + segment_sum(h[src], dst), h = [nodes | random_values]
// Round-11: counting-sort CSR build (packed part words) + quad-row aggregate:
// one wave-wide gather = 4 full 256B rows (16 lanes x uint4 per row), halving
// memory instructions vs round 9. Single [N][128] bf16 table.

#define N_NODES 100000
#define NF      128
#define FP1     129
#define M_EDGES 1600000
#define SLOTS   32                     // bucket = 32*4B = one 128B line
#define SPILL_CAP 4096

#define BINSHIFT 8
#define BINNODES 256
#define NBINS    391                   // ceil(100000/256)
#define HIST_BLOCKS 256
#define CHUNK (M_EDGES / HIST_BLOCKS)  // 6250
#define CONV_BLOCKS 12500              // 3.2M float4->ushort4 threads

// round-5 fallback params
#define NSLICES 8
#define SLICE_NODES (N_NODES / NSLICES)
#define FILL_BLOCKS 1024

__device__ inline unsigned short f2bf(float f) {
    unsigned int u = __float_as_uint(f);
    u += 0x7FFFu + ((u >> 16) & 1u);   // RNE
    return (unsigned short)(u >> 16);
}

// ---------------------------------------------------------------------------
// A: histogram blocks (LDS 391-bin hist of own chunk) + flat convert fused.
// ---------------------------------------------------------------------------
__global__ __launch_bounds__(256) void k_hist_convert(
    const float* __restrict__ nodes,
    unsigned short* __restrict__ bt,      // [N][128] bf16
    const int* __restrict__ ei,
    int* __restrict__ countsT)            // [NBINS][HIST_BLOCKS]
{
    int bid = blockIdx.x;
    if (bid >= HIST_BLOCKS) {
        int t = (bid - HIST_BLOCKS) * 256 + threadIdx.x;   // < 3,200,000 exactly
        float4 v = reinterpret_cast<const float4*>(nodes)[t];
        ushort4 o;
        o.x = f2bf(v.x); o.y = f2bf(v.y); o.z = f2bf(v.z); o.w = f2bf(v.w);
        reinterpret_cast<ushort4*>(bt)[t] = o;
        return;
    }
    __shared__ int h[NBINS];
    for (int i = threadIdx.x; i < NBINS; i += 256) h[i] = 0;
    __syncthreads();
    int e0 = bid * CHUNK;
    for (int e = e0 + threadIdx.x; e < e0 + CHUNK; e += 256)
        atomicAdd(&h[ei[e] >> BINSHIFT], 1);
    __syncthreads();
    for (int i = threadIdx.x; i < NBINS; i += 256)
        countsT[i * HIST_BLOCKS + bid] = h[i];
}

// ---------------------------------------------------------------------------
// B1: per-bin exclusive scan of the 256 block-counts (in place) + bin total.
// ---------------------------------------------------------------------------
__global__ __launch_bounds__(256) void k_scan_bins(int* __restrict__ countsT,
                                                   int* __restrict__ binTotal)
{
    __shared__ int s[256];
    int bin = blockIdx.x;
    int v = countsT[bin * HIST_BLOCKS + threadIdx.x];
    s[threadIdx.x] = v;
    __syncthreads();
    for (int off = 1; off < 256; off <<= 1) {
        int t = (threadIdx.x >= off) ? s[threadIdx.x - off] : 0;
        __syncthreads();
        s[threadIdx.x] += t;
        __syncthreads();
    }
    countsT[bin * HIST_BLOCKS + threadIdx.x] = s[threadIdx.x] - v;  // exclusive
    if (threadIdx.x == 255) binTotal[bin] = s[255];
}

// ---------------------------------------------------------------------------
// B2: single-block exclusive scan of 391 bin totals; zeroes spillCount.
// ---------------------------------------------------------------------------
__global__ __launch_bounds__(512) void k_scan_base(const int* __restrict__ binTotal,
                                                   int* __restrict__ binBase,
                                                   int* __restrict__ spillCount)
{
    __shared__ int s[512];
    int v = (threadIdx.x < NBINS) ? binTotal[threadIdx.x] : 0;
    s[threadIdx.x] = v;
    __syncthreads();
    for (int off = 1; off < 512; off <<= 1) {
        int t = (threadIdx.x >= off) ? s[threadIdx.x - off] : 0;
        __syncthreads();
        s[threadIdx.x] += t;
        __syncthreads();
    }
    if (threadIdx.x < NBINS) binBase[threadIdx.x] = s[threadIdx.x] - v;
    if (threadIdx.x == 0) { binBase[NBINS] = M_EDGES; *spillCount = 0; }
}

// ---------------------------------------------------------------------------
// C: placement via LDS cursors (disjoint segments, no global atomics).
// part entry packed: (dst&255)<<24 | src  (src < 2^17 fits).
// ---------------------------------------------------------------------------
__global__ __launch_bounds__(256) void k_place(
    const int* __restrict__ ei,
    const int* __restrict__ countsT,
    const int* __restrict__ binBase,
    unsigned int* __restrict__ part)
{
    __shared__ int cur[NBINS];
    int bid = blockIdx.x;
    for (int i = threadIdx.x; i < NBINS; i += 256)
        cur[i] = binBase[i] + countsT[i * HIST_BLOCKS + bid];
    __syncthreads();
    int e0 = bid * CHUNK;
    for (int e = e0 + threadIdx.x; e < e0 + CHUNK; e += 256) {
        int dst = ei[e];
        int src = ei[M_EDGES + e];
        int pos = atomicAdd(&cur[dst >> BINSHIFT], 1);
        part[pos] = ((unsigned)(dst & 255) << 24) | (unsigned)src;
    }
}

// ---------------------------------------------------------------------------
// D: per-bin bucket build in LDS -> dense writes.
// ---------------------------------------------------------------------------
__global__ __launch_bounds__(256) void k_bucket_build(
    const unsigned int* __restrict__ part,
    const int*   __restrict__ binBase,
    int* __restrict__ cursor,       // [N] clamped counts
    int* __restrict__ srclist,      // [N][SLOTS]
    int* __restrict__ spill,
    int* __restrict__ spillCount)
{
    __shared__ int s_cnt[BINNODES];
    __shared__ int s_bkt[BINNODES * SLOTS];   // 32 KB

    int bin = blockIdx.x;
    int nodeBase = bin << BINSHIFT;
    int nNodes = N_NODES - nodeBase;
    if (nNodes > BINNODES) nNodes = BINNODES;

    for (int i = threadIdx.x; i < BINNODES; i += 256) s_cnt[i] = 0;
    __syncthreads();

    int a = binBase[bin], b = binBase[bin + 1];
    for (int i = a + threadIdx.x; i < b; i += 256) {
        unsigned int p = part[i];
        int local = (int)(p >> 24);
        int src   = (int)(p & 0x00FFFFFFu);
        int pos = atomicAdd(&s_cnt[local], 1);
        if (pos < SLOTS) s_bkt[local * SLOTS + pos] = src;
        else {
            int sp = atomicAdd(spillCount, 1);
            if (sp < SPILL_CAP) { spill[2 * sp] = nodeBase + local; spill[2 * sp + 1] = src; }
        }
    }
    __syncthreads();

    for (int i = threadIdx.x; i < nNodes; i += 256) {
        int c = s_cnt[i];
        cursor[nodeBase + i] = (c > SLOTS) ? SLOTS : c;
    }
    for (int i = threadIdx.x; i < nNodes * SLOTS; i += 256)
        srclist[(size_t)nodeBase * SLOTS + i] = s_bkt[i];
}

// ---------------------------------------------------------------------------
// E: quad-row pull aggregation. One 64-lane wave per node; 4 groups of 16
// lanes; group grp covers edge i+grp's FULL 256B row via uint4 (16B/lane x
// 16 lanes). One wave instruction = 4 rows = 1KB (vs 2 rows in round 9).
// Bucket register-resident (lane hl holds slot hl); indices via per-lane
// __shfl. x2 unroll = 2 gathers (8 edges) in flight.
// ---------------------------------------------------------------------------
__global__ __launch_bounds__(256) void k_aggregate_q(
    const unsigned short* __restrict__ bt,   // [N][128]
    const float* __restrict__ rv,
    const int*   __restrict__ cursor,
    const int*   __restrict__ srclist,
    float* __restrict__ out)
{
    int node = (int)((blockIdx.x * (long long)blockDim.x + threadIdx.x) >> 6);
    if (node >= N_NODES) return;
    int lane = threadIdx.x & 63;
    int grp  = lane >> 4;        // 0..3: edge slot within quad
    int fq   = lane & 15;        // feature quad: features fq*8 .. fq*8+7
    int hl   = lane & 31;

    int cnt = cursor[node];
    if (cnt > SLOTS) cnt = SLOTS;
    int b = srclist[(long long)node * SLOTS + hl];   // one 128B line per node

    // rv column: masked gather + 32-wide reduce (both halves identical)
    float c = (hl < cnt) ? rv[b] : 0.f;
    c += __shfl_xor(c, 16, 32);
    c += __shfl_xor(c, 8, 32);
    c += __shfl_xor(c, 4, 32);
    c += __shfl_xor(c, 2, 32);
    c += __shfl_xor(c, 1, 32);

    float acc[8] = {0.f, 0.f, 0.f, 0.f, 0.f, 0.f, 0.f, 0.f};

    #define UNPACK_ACC(u) do {                                        \
        acc[0] += __uint_as_float((u).x << 16);                        \
        acc[1] += __uint_as_float((u).x & 0xFFFF0000u);                \
        acc[2] += __uint_as_float((u).y << 16);                        \
        acc[3] += __uint_as_float((u).y & 0xFFFF0000u);                \
        acc[4] += __uint_as_float((u).z << 16);                        \
        acc[5] += __uint_as_float((u).z & 0xFFFF0000u);                \
        acc[6] += __uint_as_float((u).w << 16);                        \
        acc[7] += __uint_as_float((u).w & 0xFFFF0000u);                \
    } while (0)

    int i = 0;
    for (; i + 7 < cnt; i += 8) {            // 8 edges per iter, 2 loads in flight
        int sa = __shfl(b, i + grp, 64);
        int sb = __shfl(b, i + 4 + grp, 64);
        uint4 ua = reinterpret_cast<const uint4*>(bt + (size_t)sa * NF)[fq];
        uint4 ub = reinterpret_cast<const uint4*>(bt + (size_t)sb * NF)[fq];
        UNPACK_ACC(ua);
        UNPACK_ACC(ub);
    }
    for (; i + 3 < cnt; i += 4) {
        int sa = __shfl(b, i + grp, 64);
        uint4 ua = reinterpret_cast<const uint4*>(bt + (size_t)sa * NF)[fq];
        UNPACK_ACC(ua);
    }
    {
        int rem = cnt - i;                   // 0..3
        int sa = __shfl(b, (i + grp < cnt) ? (i + grp) : 0, 64);  // shfl while converged
        if (grp < rem) {
            uint4 ua = reinterpret_cast<const uint4*>(bt + (size_t)sa * NF)[fq];
            UNPACK_ACC(ua);
        }
    }

    // sum the 4 groups (each fq column identical role across groups)
    #pragma unroll
    for (int k = 0; k < 8; ++k) {
        acc[k] += __shfl_xor(acc[k], 16, 64);
        acc[k] += __shfl_xor(acc[k], 32, 64);
    }

    if (lane < 16) {
        // self term (fuses the "+ h")
        uint4 su = reinterpret_cast<const uint4*>(bt + (size_t)node * NF)[fq];
        UNPACK_ACC(su);
        float* o = out + (size_t)node * FP1 + fq * 8;
        o[0] = acc[0]; o[1] = acc[1]; o[2] = acc[2]; o[3] = acc[3];
        o[4] = acc[4]; o[5] = acc[5]; o[6] = acc[6]; o[7] = acc[7];
        if (lane == 0) out[(size_t)node * FP1 + NF] = rv[node] + c;
    }
    #undef UNPACK_ACC
}

// ---------------------------------------------------------------------------
// Spill fixup: exact f32 atomic adds for bucket-overflow edges (~hundreds).
// ---------------------------------------------------------------------------
__global__ __launch_bounds__(256) void k_spill(
    const float* __restrict__ nodes, const float* __restrict__ rv,
    const int* __restrict__ spill, const int* __restrict__ spillCount,
    float* __restrict__ out)
{
    int n = *spillCount;
    if (n > SPILL_CAP) n = SPILL_CAP;
    int wave  = (int)((blockIdx.x * (long long)blockDim.x + threadIdx.x) >> 6);
    int nwave = (int)((gridDim.x * (long long)blockDim.x) >> 6);
    int lane  = threadIdx.x & 63;
    for (int e = wave; e < n; e += nwave) {
        int dst = spill[2 * e], src = spill[2 * e + 1];
        if (lane < 32) {
            float4 v = reinterpret_cast<const float4*>(nodes + (long long)src * NF)[lane];
            float* o = out + (long long)dst * FP1 + lane * 4;
            atomicAdd(o + 0, v.x); atomicAdd(o + 1, v.y);
            atomicAdd(o + 2, v.z); atomicAdd(o + 3, v.w);
        } else if (lane == 32) {
            atomicAdd(out + (long long)dst * FP1 + NF, rv[src]);
        }
    }
}

// ===========================================================================
// Fallback B: round-5 fused convert + sliced bucket fill (then k_aggregate_q).
// ===========================================================================
__global__ __launch_bounds__(256) void k_convert_fill(
    const float* __restrict__ nodes,
    unsigned short* __restrict__ bt,      // [N][128]
    const int* __restrict__ ei,
    int* __restrict__ cursor,
    int* __restrict__ srclist,
    int* __restrict__ spill,
    int* __restrict__ spillCount)
{
    int bid = blockIdx.x;
    if (bid < FILL_BLOCKS) {
        int slice = bid & (NSLICES - 1);
        int blk   = bid >> 3;
        const int nblk = FILL_BLOCKS >> 3;
        int lo = slice * SLICE_NODES, hi = lo + SLICE_NODES;
        for (int e = blk * 256 + threadIdx.x; e < M_EDGES; e += nblk * 256) {
            int dst = ei[e];
            int src = ei[M_EDGES + e];
            if (dst >= lo && dst < hi) {
                int pos = atomicAdd(&cursor[dst], 1);
                if (pos < SLOTS) srclist[dst * SLOTS + pos] = src;
                else {
                    int sp = atomicAdd(spillCount, 1);
                    if (sp < SPILL_CAP) { spill[2 * sp] = dst; spill[2 * sp + 1] = src; }
                }
            }
        }
    } else {
        int t = (bid - FILL_BLOCKS) * 256 + threadIdx.x;
        float4 v = reinterpret_cast<const float4*>(nodes)[t];
        ushort4 o;
        o.x = f2bf(v.x); o.y = f2bf(v.y); o.z = f2bf(v.z); o.w = f2bf(v.w);
        reinterpret_cast<ushort4*>(bt)[t] = o;
    }
}

// ===========================================================================
// Fallback D: atomic scatter.
// ===========================================================================
__global__ __launch_bounds__(256) void k_init_out(
    const float* __restrict__ nodes, const float* __restrict__ rv,
    float* __restrict__ out)
{
    long long idx = (long long)blockIdx.x * blockDim.x + threadIdx.x;
    const long long total = (long long)N_NODES * FP1;
    if (idx >= total) return;
    int node = (int)(idx / FP1);
    int f    = (int)(idx - (long long)node * FP1);
    out[idx] = (f < NF) ? nodes[(long long)node * NF + f] : rv[node];
}

__global__ __launch_bounds__(256) void k_scatter(
    const float* __restrict__ nodes, const float* __restrict__ rv,
    const int* __restrict__ ei, float* __restrict__ out)
{
    long long t = (long long)blockIdx.x * blockDim.x + threadIdx.x;
    int lane = (int)(t & 31);
    long long e = t >> 5;
    if (e >= M_EDGES) return;
    int dst = ei[e];
    int src = ei[M_EDGES + e];
    const float4* row = reinterpret_cast<const float4*>(nodes + (long long)src * NF);
    float4 v = row[lane];
    float* o = out + (long long)dst * FP1 + lane * 4;
    atomicAdd(o + 0, v.x); atomicAdd(o + 1, v.y);
    atomicAdd(o + 2, v.z); atomicAdd(o + 3, v.w);
    if (lane == 0) atomicAdd(out + (long long)dst * FP1 + NF, rv[src]);
}

extern "C" void kernel_launch(void* const* d_in, const int* in_sizes, int n_in,
                              void* d_out, int out_size, void* d_ws, size_t ws_size,
                              hipStream_t stream) {
    const float* nodes = (const float*)d_in[0];
    const int*   ei    = (const int*)d_in[1];
    const float* rv    = (const float*)d_in[2];
    float* out = (float*)d_out;

    const size_t bt_bytes     = (size_t)N_NODES * NF * 2;            // 25.6 MB
    const size_t part_bytes   = (size_t)M_EDGES * 4;                 // 6.4 MB (packed)
    const size_t srcl_bytes   = (size_t)N_NODES * SLOTS * 4;         // 12.8 MB
    const size_t cur_bytes    = (size_t)N_NODES * 4;                 // 0.4 MB
    const size_t countsT_b    = (size_t)NBINS * HIST_BLOCKS * 4;     // 0.4 MB
    const size_t binTotal_b   = (size_t)NBINS * 4;
    const size_t binBase_b    = (size_t)(NBINS + 1) * 4;
    const size_t spill_bytes  = (size_t)SPILL_CAP * 8;

    const size_t need_A = bt_bytes + part_bytes + srcl_bytes + cur_bytes
                        + countsT_b + binTotal_b + binBase_b + 4 + spill_bytes + 256;
    const size_t need_B = bt_bytes + cur_bytes + srcl_bytes + spill_bytes + 64;

    if (ws_size >= need_A) {
        // --- Path A: counting-sort CSR + quad-row aggregate ---
        char* w = (char*)d_ws;
        unsigned short* bt = (unsigned short*)w; w += bt_bytes;
        unsigned int* part = (unsigned int*)w;   w += part_bytes;
        int* srclist    = (int*)w;   w += srcl_bytes;
        int* cursor     = (int*)w;   w += cur_bytes;
        int* countsT    = (int*)w;   w += countsT_b;
        int* binTotal   = (int*)w;   w += binTotal_b;
        int* binBase    = (int*)w;   w += binBase_b;
        int* spillCount = (int*)w;   w += 4;
        int* spill      = (int*)w;

        k_hist_convert<<<HIST_BLOCKS + CONV_BLOCKS, 256, 0, stream>>>(
            nodes, bt, ei, countsT);
        k_scan_bins<<<NBINS, 256, 0, stream>>>(countsT, binTotal);
        k_scan_base<<<1, 512, 0, stream>>>(binTotal, binBase, spillCount);
        k_place<<<HIST_BLOCKS, 256, 0, stream>>>(ei, countsT, binBase, part);
        k_bucket_build<<<NBINS, 256, 0, stream>>>(
            part, binBase, cursor, srclist, spill, spillCount);

        long long threads = (long long)N_NODES * 64;
        int grid = (int)((threads + 255) / 256);
        k_aggregate_q<<<grid, 256, 0, stream>>>(bt, rv, cursor, srclist, out);

        k_spill<<<16, 256, 0, stream>>>(nodes, rv, spill, spillCount, out);
    } else if (ws_size >= need_B) {
        // --- Path B: round-5 fused pipeline ---
        char* w = (char*)d_ws;
        unsigned short* bt = (unsigned short*)w; w += bt_bytes;
        int* cursor     = (int*)w; w += cur_bytes;
        int* srclist    = (int*)w; w += srcl_bytes;
        int* spill      = (int*)w; w += spill_bytes;
        int* spillCount = (int*)w;

        hipMemsetAsync(cursor, 0, cur_bytes, stream);
        hipMemsetAsync(spillCount, 0, 4, stream);

        k_convert_fill<<<FILL_BLOCKS + CONV_BLOCKS, 256, 0, stream>>>(
            nodes, bt, ei, cursor, srclist, spill, spillCount);

        long long threads = (long long)N_NODES * 64;
        int grid = (int)((threads + 255) / 256);
        k_aggregate_q<<<grid, 256, 0, stream>>>(bt, rv, cursor, srclist, out);

        k_spill<<<16, 256, 0, stream>>>(nodes, rv, spill, spillCount, out);
    } else {
        // --- Path D: atomic scatter ---
        long long total = (long long)N_NODES * FP1;
        k_init_out<<<(int)((total + 255) / 256), 256, 0, stream>>>(nodes, rv, out);
        long long threads = (long long)M_EDGES * 32;
        k_scatter<<<(int)((threads + 255) / 256), 256, 0, stream>>>(nodes, rv, ei, out);
    }
}

// Round 12
// 119.125 us; speedup vs baseline: 1.2806x; 1.0040x over previous
//
#include <hip/hip_runtime.h>

// rGIN fused: out = h + segment_sum(h[src], dst), h = [nodes | random_values]
// Round-12: counting-sort CSR build (round-11, proven) + quad-row aggregate
// with 16-edge unroll: 4 wave-wide uint4 gathers (4KB) in flight per wave to
// double outstanding-miss parallelism on the L2-fill path.

#define N_NODES 100000
#define NF      128
#define FP1     129
#define M_EDGES 1600000
#define SLOTS   32                     // bucket = 32*4B = one 128B line
#define SPILL_CAP 4096

#define BINSHIFT 8
#define BINNODES 256
#define NBINS    391                   // ceil(100000/256)
#define HIST_BLOCKS 256
#define CHUNK (M_EDGES / HIST_BLOCKS)  // 6250
#define CONV_BLOCKS 12500              // 3.2M float4->ushort4 threads

// round-5 fallback params
#define NSLICES 8
#define SLICE_NODES (N_NODES / NSLICES)
#define FILL_BLOCKS 1024

__device__ inline unsigned short f2bf(float f) {
    unsigned int u = __float_as_uint(f);
    u += 0x7FFFu + ((u >> 16) & 1u);   // RNE
    return (unsigned short)(u >> 16);
}

// ---------------------------------------------------------------------------
// A: histogram blocks (LDS 391-bin hist of own chunk) + flat convert fused.
// ---------------------------------------------------------------------------
__global__ __launch_bounds__(256) void k_hist_convert(
    const float* __restrict__ nodes,
    unsigned short* __restrict__ bt,      // [N][128] bf16
    const int* __restrict__ ei,
    int* __restrict__ countsT)            // [NBINS][HIST_BLOCKS]
{
    int bid = blockIdx.x;
    if (bid >= HIST_BLOCKS) {
        int t = (bid - HIST_BLOCKS) * 256 + threadIdx.x;   // < 3,200,000 exactly
        float4 v = reinterpret_cast<const float4*>(nodes)[t];
        ushort4 o;
        o.x = f2bf(v.x); o.y = f2bf(v.y); o.z = f2bf(v.z); o.w = f2bf(v.w);
        reinterpret_cast<ushort4*>(bt)[t] = o;
        return;
    }
    __shared__ int h[NBINS];
    for (int i = threadIdx.x; i < NBINS; i += 256) h[i] = 0;
    __syncthreads();
    int e0 = bid * CHUNK;
    for (int e = e0 + threadIdx.x; e < e0 + CHUNK; e += 256)
        atomicAdd(&h[ei[e] >> BINSHIFT], 1);
    __syncthreads();
    for (int i = threadIdx.x; i < NBINS; i += 256)
        countsT[i * HIST_BLOCKS + bid] = h[i];
}

// ---------------------------------------------------------------------------
// B1: per-bin exclusive scan of the 256 block-counts (in place) + bin total.
// ---------------------------------------------------------------------------
__global__ __launch_bounds__(256) void k_scan_bins(int* __restrict__ countsT,
                                                   int* __restrict__ binTotal)
{
    __shared__ int s[256];
    int bin = blockIdx.x;
    int v = countsT[bin * HIST_BLOCKS + threadIdx.x];
    s[threadIdx.x] = v;
    __syncthreads();
    for (int off = 1; off < 256; off <<= 1) {
        int t = (threadIdx.x >= off) ? s[threadIdx.x - off] : 0;
        __syncthreads();
        s[threadIdx.x] += t;
        __syncthreads();
    }
    countsT[bin * HIST_BLOCKS + threadIdx.x] = s[threadIdx.x] - v;  // exclusive
    if (threadIdx.x == 255) binTotal[bin] = s[255];
}

// ---------------------------------------------------------------------------
// B2: single-block exclusive scan of 391 bin totals; zeroes spillCount.
// ---------------------------------------------------------------------------
__global__ __launch_bounds__(512) void k_scan_base(const int* __restrict__ binTotal,
                                                   int* __restrict__ binBase,
                                                   int* __restrict__ spillCount)
{
    __shared__ int s[512];
    int v = (threadIdx.x < NBINS) ? binTotal[threadIdx.x] : 0;
    s[threadIdx.x] = v;
    __syncthreads();
    for (int off = 1; off < 512; off <<= 1) {
        int t = (threadIdx.x >= off) ? s[threadIdx.x - off] : 0;
        __syncthreads();
        s[threadIdx.x] += t;
        __syncthreads();
    }
    if (threadIdx.x < NBINS) binBase[threadIdx.x] = s[threadIdx.x] - v;
    if (threadIdx.x == 0) { binBase[NBINS] = M_EDGES; *spillCount = 0; }
}

// ---------------------------------------------------------------------------
// C: placement via LDS cursors (disjoint segments, no global atomics).
// part entry packed: (dst&255)<<24 | src  (src < 2^17 fits).
// ---------------------------------------------------------------------------
__global__ __launch_bounds__(256) void k_place(
    const int* __restrict__ ei,
    const int* __restrict__ countsT,
    const int* __restrict__ binBase,
    unsigned int* __restrict__ part)
{
    __shared__ int cur[NBINS];
    int bid = blockIdx.x;
    for (int i = threadIdx.x; i < NBINS; i += 256)
        cur[i] = binBase[i] + countsT[i * HIST_BLOCKS + bid];
    __syncthreads();
    int e0 = bid * CHUNK;
    for (int e = e0 + threadIdx.x; e < e0 + CHUNK; e += 256) {
        int dst = ei[e];
        int src = ei[M_EDGES + e];
        int pos = atomicAdd(&cur[dst >> BINSHIFT], 1);
        part[pos] = ((unsigned)(dst & 255) << 24) | (unsigned)src;
    }
}

// ---------------------------------------------------------------------------
// D: per-bin bucket build in LDS -> dense writes.
// ---------------------------------------------------------------------------
__global__ __launch_bounds__(256) void k_bucket_build(
    const unsigned int* __restrict__ part,
    const int*   __restrict__ binBase,
    int* __restrict__ cursor,       // [N] clamped counts
    int* __restrict__ srclist,      // [N][SLOTS]
    int* __restrict__ spill,
    int* __restrict__ spillCount)
{
    __shared__ int s_cnt[BINNODES];
    __shared__ int s_bkt[BINNODES * SLOTS];   // 32 KB

    int bin = blockIdx.x;
    int nodeBase = bin << BINSHIFT;
    int nNodes = N_NODES - nodeBase;
    if (nNodes > BINNODES) nNodes = BINNODES;

    for (int i = threadIdx.x; i < BINNODES; i += 256) s_cnt[i] = 0;
    __syncthreads();

    int a = binBase[bin], b = binBase[bin + 1];
    for (int i = a + threadIdx.x; i < b; i += 256) {
        unsigned int p = part[i];
        int local = (int)(p >> 24);
        int src   = (int)(p & 0x00FFFFFFu);
        int pos = atomicAdd(&s_cnt[local], 1);
        if (pos < SLOTS) s_bkt[local * SLOTS + pos] = src;
        else {
            int sp = atomicAdd(spillCount, 1);
            if (sp < SPILL_CAP) { spill[2 * sp] = nodeBase + local; spill[2 * sp + 1] = src; }
        }
    }
    __syncthreads();

    for (int i = threadIdx.x; i < nNodes; i += 256) {
        int c = s_cnt[i];
        cursor[nodeBase + i] = (c > SLOTS) ? SLOTS : c;
    }
    for (int i = threadIdx.x; i < nNodes * SLOTS; i += 256)
        srclist[(size_t)nodeBase * SLOTS + i] = s_bkt[i];
}

// ---------------------------------------------------------------------------
// E: quad-row pull aggregation, 16-edge unroll (4 gathers in flight).
// One 64-lane wave per node; 4 groups of 16 lanes; group grp covers one
// edge's FULL 256B row via uint4 (16B/lane x 16 lanes). Bucket register-
// resident (lane hl holds slot hl); indices broadcast via __shfl.
// ---------------------------------------------------------------------------
__global__ __launch_bounds__(256) void k_aggregate_q(
    const unsigned short* __restrict__ bt,   // [N][128]
    const float* __restrict__ rv,
    const int*   __restrict__ cursor,
    const int*   __restrict__ srclist,
    float* __restrict__ out)
{
    int node = (int)((blockIdx.x * (long long)blockDim.x + threadIdx.x) >> 6);
    if (node >= N_NODES) return;
    int lane = threadIdx.x & 63;
    int grp  = lane >> 4;        // 0..3: edge slot within quad
    int fq   = lane & 15;        // feature quad: features fq*8 .. fq*8+7
    int hl   = lane & 31;

    int cnt = cursor[node];
    if (cnt > SLOTS) cnt = SLOTS;
    int b = srclist[(long long)node * SLOTS + hl];   // one 128B line per node

    // rv column: masked gather + 32-wide reduce (both halves identical)
    float c = (hl < cnt) ? rv[b] : 0.f;
    c += __shfl_xor(c, 16, 32);
    c += __shfl_xor(c, 8, 32);
    c += __shfl_xor(c, 4, 32);
    c += __shfl_xor(c, 2, 32);
    c += __shfl_xor(c, 1, 32);

    float acc[8] = {0.f, 0.f, 0.f, 0.f, 0.f, 0.f, 0.f, 0.f};

    #define UNPACK_ACC(u) do {                                        \
        acc[0] += __uint_as_float((u).x << 16);                        \
        acc[1] += __uint_as_float((u).x & 0xFFFF0000u);                \
        acc[2] += __uint_as_float((u).y << 16);                        \
        acc[3] += __uint_as_float((u).y & 0xFFFF0000u);                \
        acc[4] += __uint_as_float((u).z << 16);                        \
        acc[5] += __uint_as_float((u).z & 0xFFFF0000u);                \
        acc[6] += __uint_as_float((u).w << 16);                        \
        acc[7] += __uint_as_float((u).w & 0xFFFF0000u);                \
    } while (0)

    int i = 0;
    for (; i + 15 < cnt; i += 16) {          // 16 edges, 4 gathers in flight
        int s0 = __shfl(b, i + grp,      64);
        int s1 = __shfl(b, i + 4 + grp,  64);
        int s2 = __shfl(b, i + 8 + grp,  64);
        int s3 = __shfl(b, i + 12 + grp, 64);
        uint4 u0 = reinterpret_cast<const uint4*>(bt + (size_t)s0 * NF)[fq];
        uint4 u1 = reinterpret_cast<const uint4*>(bt + (size_t)s1 * NF)[fq];
        uint4 u2 = reinterpret_cast<const uint4*>(bt + (size_t)s2 * NF)[fq];
        uint4 u3 = reinterpret_cast<const uint4*>(bt + (size_t)s3 * NF)[fq];
        UNPACK_ACC(u0);
        UNPACK_ACC(u1);
        UNPACK_ACC(u2);
        UNPACK_ACC(u3);
    }
    for (; i + 7 < cnt; i += 8) {            // 8 edges, 2 gathers in flight
        int s0 = __shfl(b, i + grp,     64);
        int s1 = __shfl(b, i + 4 + grp, 64);
        uint4 u0 = reinterpret_cast<const uint4*>(bt + (size_t)s0 * NF)[fq];
        uint4 u1 = reinterpret_cast<const uint4*>(bt + (size_t)s1 * NF)[fq];
        UNPACK_ACC(u0);
        UNPACK_ACC(u1);
    }
    for (; i + 3 < cnt; i += 4) {
        int s0 = __shfl(b, i + grp, 64);
        uint4 u0 = reinterpret_cast<const uint4*>(bt + (size_t)s0 * NF)[fq];
        UNPACK_ACC(u0);
    }
    {
        int rem = cnt - i;                   // 0..3
        int sa = __shfl(b, (i + grp < cnt) ? (i + grp) : 0, 64);  // shfl while converged
        if (grp < rem) {
            uint4 ua = reinterpret_cast<const uint4*>(bt + (size_t)sa * NF)[fq];
            UNPACK_ACC(ua);
        }
    }

    // sum the 4 groups (each fq column identical role across groups)
    #pragma unroll
    for (int k = 0; k < 8; ++k) {
        acc[k] += __shfl_xor(acc[k], 16, 64);
        acc[k] += __shfl_xor(acc[k], 32, 64);
    }

    if (lane < 16) {
        // self term (fuses the "+ h")
        uint4 su = reinterpret_cast<const uint4*>(bt + (size_t)node * NF)[fq];
        UNPACK_ACC(su);
        float* o = out + (size_t)node * FP1 + fq * 8;
        o[0] = acc[0]; o[1] = acc[1]; o[2] = acc[2]; o[3] = acc[3];
        o[4] = acc[4]; o[5] = acc[5]; o[6] = acc[6]; o[7] = acc[7];
        if (lane == 0) out[(size_t)node * FP1 + NF] = rv[node] + c;
    }
    #undef UNPACK_ACC
}

// ---------------------------------------------------------------------------
// Spill fixup: exact f32 atomic adds for bucket-overflow edges (~hundreds).
// ---------------------------------------------------------------------------
__global__ __launch_bounds__(256) void k_spill(
    const float* __restrict__ nodes, const float* __restrict__ rv,
    const int* __restrict__ spill, const int* __restrict__ spillCount,
    float* __restrict__ out)
{
    int n = *spillCount;
    if (n > SPILL_CAP) n = SPILL_CAP;
    int wave  = (int)((blockIdx.x * (long long)blockDim.x + threadIdx.x) >> 6);
    int nwave = (int)((gridDim.x * (long long)blockDim.x) >> 6);
    int lane  = threadIdx.x & 63;
    for (int e = wave; e < n; e += nwave) {
        int dst = spill[2 * e], src = spill[2 * e + 1];
        if (lane < 32) {
            float4 v = reinterpret_cast<const float4*>(nodes + (long long)src * NF)[lane];
            float* o = out + (long long)dst * FP1 + lane * 4;
            atomicAdd(o + 0, v.x); atomicAdd(o + 1, v.y);
            atomicAdd(o + 2, v.z); atomicAdd(o + 3, v.w);
        } else if (lane == 32) {
            atomicAdd(out + (long long)dst * FP1 + NF, rv[src]);
        }
    }
}

// ===========================================================================
// Fallback B: round-5 fused convert + sliced bucket fill (then k_aggregate_q).
// ===========================================================================
__global__ __launch_bounds__(256) void k_convert_fill(
    const float* __restrict__ nodes,
    unsigned short* __restrict__ bt,      // [N][128]
    const int* __restrict__ ei,
    int* __restrict__ cursor,
    int* __restrict__ srclist,
    int* __restrict__ spill,
    int* __restrict__ spillCount)
{
    int bid = blockIdx.x;
    if (bid < FILL_BLOCKS) {
        int slice = bid & (NSLICES - 1);
        int blk   = bid >> 3;
        const int nblk = FILL_BLOCKS >> 3;
        int lo = slice * SLICE_NODES, hi = lo + SLICE_NODES;
        for (int e = blk * 256 + threadIdx.x; e < M_EDGES; e += nblk * 256) {
            int dst = ei[e];
            int src = ei[M_EDGES + e];
            if (dst >= lo && dst < hi) {
                int pos = atomicAdd(&cursor[dst], 1);
                if (pos < SLOTS) srclist[dst * SLOTS + pos] = src;
                else {
                    int sp = atomicAdd(spillCount, 1);
                    if (sp < SPILL_CAP) { spill[2 * sp] = dst; spill[2 * sp + 1] = src; }
                }
            }
        }
    } else {
        int t = (bid - FILL_BLOCKS) * 256 + threadIdx.x;
        float4 v = reinterpret_cast<const float4*>(nodes)[t];
        ushort4 o;
        o.x = f2bf(v.x); o.y = f2bf(v.y); o.z = f2bf(v.z); o.w = f2bf(v.w);
        reinterpret_cast<ushort4*>(bt)[t] = o;
    }
}

// ===========================================================================
// Fallback D: atomic scatter.
// ===========================================================================
__global__ __launch_bounds__(256) void k_init_out(
    const float* __restrict__ nodes, const float* __restrict__ rv,
    float* __restrict__ out)
{
    long long idx = (long long)blockIdx.x * blockDim.x + threadIdx.x;
    const long long total = (long long)N_NODES * FP1;
    if (idx >= total) return;
    int node = (int)(idx / FP1);
    int f    = (int)(idx - (long long)node * FP1);
    out[idx] = (f < NF) ? nodes[(long long)node * NF + f] : rv[node];
}

__global__ __launch_bounds__(256) void k_scatter(
    const float* __restrict__ nodes, const float* __restrict__ rv,
    const int* __restrict__ ei, float* __restrict__ out)
{
    long long t = (long long)blockIdx.x * blockDim.x + threadIdx.x;
    int lane = (int)(t & 31);
    long long e = t >> 5;
    if (e >= M_EDGES) return;
    int dst = ei[e];
    int src = ei[M_EDGES + e];
    const float4* row = reinterpret_cast<const float4*>(nodes + (long long)src * NF);
    float4 v = row[lane];
    float* o = out + (long long)dst * FP1 + lane * 4;
    atomicAdd(o + 0, v.x); atomicAdd(o + 1, v.y);
    atomicAdd(o + 2, v.z); atomicAdd(o + 3, v.w);
    if (lane == 0) atomicAdd(out + (long long)dst * FP1 + NF, rv[src]);
}

extern "C" void kernel_launch(void* const* d_in, const int* in_sizes, int n_in,
                              void* d_out, int out_size, void* d_ws, size_t ws_size,
                              hipStream_t stream) {
    const float* nodes = (const float*)d_in[0];
    const int*   ei    = (const int*)d_in[1];
    const float* rv    = (const float*)d_in[2];
    float* out = (float*)d_out;

    const size_t bt_bytes     = (size_t)N_NODES * NF * 2;            // 25.6 MB
    const size_t part_bytes   = (size_t)M_EDGES * 4;                 // 6.4 MB (packed)
    const size_t srcl_bytes   = (size_t)N_NODES * SLOTS * 4;         // 12.8 MB
    const size_t cur_bytes    = (size_t)N_NODES * 4;                 // 0.4 MB
    const size_t countsT_b    = (size_t)NBINS * HIST_BLOCKS * 4;     // 0.4 MB
    const size_t binTotal_b   = (size_t)NBINS * 4;
    const size_t binBase_b    = (size_t)(NBINS + 1) * 4;
    const size_t spill_bytes  = (size_t)SPILL_CAP * 8;

    const size_t need_A = bt_bytes + part_bytes + srcl_bytes + cur_bytes
                        + countsT_b + binTotal_b + binBase_b + 4 + spill_bytes + 256;
    const size_t need_B = bt_bytes + cur_bytes + srcl_bytes + spill_bytes + 64;

    if (ws_size >= need_A) {
        // --- Path A: counting-sort CSR + quad-row aggregate (unroll 16) ---
        char* w = (char*)d_ws;
        unsigned short* bt = (unsigned short*)w; w += bt_bytes;
        unsigned int* part = (unsigned int*)w;   w += part_bytes;
        int* srclist    = (int*)w;   w += srcl_bytes;
        int* cursor     = (int*)w;   w += cur_bytes;
        int* countsT    = (int*)w;   w += countsT_b;
        int* binTotal   = (int*)w;   w += binTotal_b;
        int* binBase    = (int*)w;   w += binBase_b;
        int* spillCount = (int*)w;   w += 4;
        int* spill      = (int*)w;

        k_hist_convert<<<HIST_BLOCKS + CONV_BLOCKS, 256, 0, stream>>>(
            nodes, bt, ei, countsT);
        k_scan_bins<<<NBINS, 256, 0, stream>>>(countsT, binTotal);
        k_scan_base<<<1, 512, 0, stream>>>(binTotal, binBase, spillCount);
        k_place<<<HIST_BLOCKS, 256, 0, stream>>>(ei, countsT, binBase, part);
        k_bucket_build<<<NBINS, 256, 0, stream>>>(
            part, binBase, cursor, srclist, spill, spillCount);

        long long threads = (long long)N_NODES * 64;
        int grid = (int)((threads + 255) / 256);
        k_aggregate_q<<<grid, 256, 0, stream>>>(bt, rv, cursor, srclist, out);

        k_spill<<<16, 256, 0, stream>>>(nodes, rv, spill, spillCount, out);
    } else if (ws_size >= need_B) {
        // --- Path B: round-5 fused pipeline ---
        char* w = (char*)d_ws;
        unsigned short* bt = (unsigned short*)w; w += bt_bytes;
        int* cursor     = (int*)w; w += cur_bytes;
        int* srclist    = (int*)w; w += srcl_bytes;
        int* spill      = (int*)w; w += spill_bytes;
        int* spillCount = (int*)w;

        hipMemsetAsync(cursor, 0, cur_bytes, stream);
        hipMemsetAsync(spillCount, 0, 4, stream);

        k_convert_fill<<<FILL_BLOCKS + CONV_BLOCKS, 256, 0, stream>>>(
            nodes, bt, ei, cursor, srclist, spill, spillCount);

        long long threads = (long long)N_NODES * 64;
        int grid = (int)((threads + 255) / 256);
        k_aggregate_q<<<grid, 256, 0, stream>>>(bt, rv, cursor, srclist, out);

        k_spill<<<16, 256, 0, stream>>>(nodes, rv, spill, spillCount, out);
    } else {
        // --- Path D: atomic scatter ---
        long long total = (long long)N_NODES * FP1;
        k_init_out<<<(int)((total + 255) / 256), 256, 0, stream>>>(nodes, rv, out);
        long long threads = (long long)M_EDGES * 32;
        k_scatter<<<(int)((threads + 255) / 256), 256, 0, stream>>>(nodes, rv, ei, out);
    }
}